// Round 4
// baseline (25390.053 us; speedup 1.0000x reference)
//
#include <hip/hip_runtime.h>
#include <hip/hip_bf16.h>

typedef __hip_bfloat16 bf16;

__device__ __forceinline__ float b2f(bf16 x){ return __bfloat162float(x); }
__device__ __forceinline__ bf16 f2b(float x){ return __float2bfloat16(x); }

constexpr int Nn = 8, Cc = 512, Tt = 4096, Gg = 32, CPG = 16;
constexpr float EPS = 1e-5f;

// ---------------- Stage 1: conv1d 512->512 k=3 pad=1, bias. fp32 in, bf16 out (ws) ----------------
__global__ void k_conv1(const float* __restrict__ feat, const float* __restrict__ w,
                        const float* __restrict__ bias, bf16* __restrict__ out) {
    int idx = blockIdx.x * 256 + threadIdx.x;      // N*C*T = 2^24 threads, t fastest
    int t = idx & (Tt - 1);
    int o = (idx >> 12) & (Cc - 1);
    int n = idx >> 21;
    const float* frow = feat + ((size_t)n * Cc) * Tt + t;
    const float* wrow = w + (size_t)o * Cc * 3;
    float acc = bias[o];
    bool tm = (t > 0), tp = (t < Tt - 1);
    for (int i = 0; i < Cc; ++i) {
        const float* f = frow + (size_t)i * Tt;
        float xm = tm ? f[-1] : 0.f;
        float x0 = f[0];
        float xp = tp ? f[1] : 0.f;
        acc += xm * wrow[3*i] + x0 * wrow[3*i+1] + xp * wrow[3*i+2];
    }
    out[idx] = f2b(acc);
}

// ---------------- Stage 2a: group-norm stats per (n,g) over 16ch x 4096t ----------------
__global__ void k_gnstats(const bf16* __restrict__ x, float* __restrict__ mean,
                          float* __restrict__ rstd) {
    int blk = blockIdx.x;                 // n*32 + g
    const bf16* base = x + (size_t)blk * CPG * Tt;  // contiguous 16*4096 (C-major layout)
    float s = 0.f, ss = 0.f;
    for (int j = threadIdx.x; j < CPG * Tt; j += 256) {
        float v = b2f(base[j]);
        s += v; ss += v * v;
    }
    __shared__ float sh[512];
    sh[threadIdx.x] = s; sh[256 + threadIdx.x] = ss;
    __syncthreads();
    for (int off = 128; off > 0; off >>= 1) {
        if (threadIdx.x < off) {
            sh[threadIdx.x] += sh[threadIdx.x + off];
            sh[256 + threadIdx.x] += sh[256 + threadIdx.x + off];
        }
        __syncthreads();
    }
    if (threadIdx.x == 0) {
        float m = sh[0] / (float)(CPG * Tt);
        float v = sh[256] / (float)(CPG * Tt) - m * m;
        mean[blk] = m;
        rstd[blk] = rsqrtf(v + EPS);
    }
}

// ---------------- Stage 2b: normalize + affine + relu, in place ----------------
__global__ void k_gnapply(bf16* __restrict__ x, const float* __restrict__ mean,
                          const float* __restrict__ rstd, const float* __restrict__ gamma,
                          const float* __restrict__ beta) {
    int idx = blockIdx.x * 256 + threadIdx.x;
    int c = (idx >> 12) & (Cc - 1);
    int n = idx >> 21;
    int blk = n * Gg + (c / CPG);
    float v = (b2f(x[idx]) - mean[blk]) * rstd[blk] * gamma[c] + beta[c];
    x[idx] = f2b(fmaxf(v, 0.f));
}

// ---- stride parse (robust: int32 expected; fp32/f64 fallback; default 8) ----
__device__ __forceinline__ float stride_inv(const void* sp){
    int si = *(const int*)sp;
    if (si >= 1 && si <= 100000) return 1.0f / (float)si;
    float sf = *(const float*)sp;
    if (sf >= 0.5f && sf <= 1.0e5f) return 1.0f / sf;
    if (si == 0){
        double sd = *(const double*)sp;
        if (sd >= 0.5 && sd <= 1.0e5) return (float)(1.0 / sd);
    }
    return 0.125f;
}

// ---------------- Stage 3: deformable conv k=3 + bias + relu, fp32 out ----------------
// off_y = [-y1, 0, +y2]; k=1 tap is exact integer position t (w1==0).
__global__ void k_deform(const bf16* __restrict__ h, const float* __restrict__ locs,
                         const float* __restrict__ w, const float* __restrict__ bias,
                         const void* __restrict__ stride_p, float* __restrict__ out) {
    int idx = blockIdx.x * 256 + threadIdx.x;      // N*C*T, t fastest
    int t = idx & (Tt - 1);
    int o = (idx >> 12) & (Cc - 1);
    int n = idx >> 21;
    float inv = stride_inv(stride_p);
    float y1 = locs[((size_t)n * 2 + 0) * Tt + t] * inv;
    float y2 = locs[((size_t)n * 2 + 1) * Tt + t] * inv;
    float pos0 = (float)(t - 1) - y1;              // k=0
    float pos2 = (float)(t + 1) + y2;              // k=2
    float p00 = floorf(pos0), p20 = floorf(pos2);
    float w10 = pos0 - p00, w12 = pos2 - p20;
    int a0 = (int)p00, a1 = a0 + 1;
    int c0 = (int)p20, c1 = c0 + 1;
    bool va0 = (a0 >= 0) & (a0 < Tt), va1 = (a1 >= 0) & (a1 < Tt);
    bool vc0 = (c0 >= 0) & (c0 < Tt), vc1 = (c1 >= 0) & (c1 < Tt);
    int a0c = min(max(a0, 0), Tt - 1), a1c = min(max(a1, 0), Tt - 1);
    int c0c = min(max(c0, 0), Tt - 1), c1c = min(max(c1, 0), Tt - 1);
    const bf16* hbase = h + ((size_t)n * Cc) * Tt;
    const float* wrow = w + (size_t)o * Cc * 3;
    float acc = bias[o];
    for (int i = 0; i < Cc; ++i) {
        const bf16* hr = hbase + (size_t)i * Tt;
        float s00 = va0 ? b2f(hr[a0c]) : 0.f;
        float s01 = va1 ? b2f(hr[a1c]) : 0.f;
        float mid = b2f(hr[t]);
        float s20 = vc0 ? b2f(hr[c0c]) : 0.f;
        float s21 = vc1 ? b2f(hr[c1c]) : 0.f;
        float samp0 = s00 + w10 * (s01 - s00);   // masked values are exactly 0 -> matches ref
        float samp2 = s20 + w12 * (s21 - s20);
        acc += samp0 * wrow[3*i] + mid * wrow[3*i+1] + samp2 * wrow[3*i+2];
    }
    out[idx] = fmaxf(acc, 0.f);
}

// ---------------- Stage 4: conv1d 512->2 k=3 pad=1, bias. fp32 in/out ----------------
__global__ void k_outconv(const float* __restrict__ x, const float* __restrict__ w,
                          const float* __restrict__ bias, float* __restrict__ out) {
    int idx = blockIdx.x * 256 + threadIdx.x;      // N*2*T = 65536
    int t = idx & (Tt - 1);
    int o = (idx >> 12) & 1;
    int n = idx >> 13;
    const float* xb = x + ((size_t)n * Cc) * Tt + t;
    const float* wrow = w + (size_t)o * Cc * 3;
    float acc = bias[o];
    bool tm = (t > 0), tp = (t < Tt - 1);
    for (int i = 0; i < Cc; ++i) {
        const float* f = xb + (size_t)i * Tt;
        float xm = tm ? f[-1] : 0.f;
        float x0 = f[0];
        float xp = tp ? f[1] : 0.f;
        acc += xm * wrow[3*i] + x0 * wrow[3*i+1] + xp * wrow[3*i+2];
    }
    out[idx] = acc;
}

extern "C" void kernel_launch(void* const* d_in, const int* in_sizes, int n_in,
                              void* d_out, int out_size, void* d_ws, size_t ws_size,
                              hipStream_t stream) {
    const float* feat   = (const float*)d_in[0];
    const float* locs   = (const float*)d_in[1];
    const float* conv_w = (const float*)d_in[2];
    const float* conv_b = (const float*)d_in[3];
    const float* gn_g   = (const float*)d_in[4];
    const float* gn_b   = (const float*)d_in[5];
    const float* dcn_w  = (const float*)d_in[6];
    const float* dcn_b  = (const float*)d_in[7];
    const float* out_w  = (const float*)d_in[8];
    const float* out_b  = (const float*)d_in[9];

    float* offset      = (float*)d_out;                        // (8,2,4096) fp32
    float* offset_feat = (float*)d_out + (size_t)Nn * 2 * Tt;  // (8,512,4096) fp32

    float* mean = (float*)d_ws;                                // 256 floats
    float* rstd = mean + 256;                                  // 256 floats
    bf16*  h    = (bf16*)((char*)d_ws + 4096);                 // (8,512,4096) bf16 = 32 MB

    const int NCT_BLOCKS = (Nn * Cc * Tt) / 256;               // 65536

    k_conv1  <<<NCT_BLOCKS, 256, 0, stream>>>(feat, conv_w, conv_b, h);
    k_gnstats<<<Nn * Gg,    256, 0, stream>>>(h, mean, rstd);
    k_gnapply<<<NCT_BLOCKS, 256, 0, stream>>>(h, mean, rstd, gn_g, gn_b);
    k_deform <<<NCT_BLOCKS, 256, 0, stream>>>(h, locs, dcn_w, dcn_b, d_in[10], offset_feat);
    k_outconv<<<(Nn * 2 * Tt) / 256, 256, 0, stream>>>(offset_feat, out_w, out_b, offset);
}

// Round 5
// 1053.941 us; speedup vs baseline: 24.0906x; 24.0906x over previous
//
#include <hip/hip_runtime.h>
#include <hip/hip_bf16.h>

typedef __hip_bfloat16 bf16;
typedef __attribute__((ext_vector_type(8))) short short8;   // 8 bf16 = 4 VGPR (MFMA A/B frag)
typedef __attribute__((ext_vector_type(4))) short short4v;
typedef __attribute__((ext_vector_type(4))) float float4v;

constexpr int Nn = 8, Cc = 512, Tt = 4096, Gg = 32, CPG = 16;
constexpr float EPS = 1e-5f;
constexpr int TM = 128, TN = 128, KI = 32, KC = 96, RS = 104; // RS: LDS row stride (shorts)

__device__ __forceinline__ float b2f(bf16 x){ return __bfloat162float(x); }
__device__ __forceinline__ bf16  f2b(float x){ return __float2bfloat16(x); }
__device__ __forceinline__ short f2s(float x){
    union { bf16 b; short s; } u; u.b = f2b(x); return u.s;
}

__device__ __forceinline__ float stride_val(const void* sp){
    int si = *(const int*)sp;
    if (si >= 1 && si <= 100000) return (float)si;
    float sf = *(const float*)sp;
    if (sf >= 0.5f && sf <= 1.0e5f) return sf;
    return 8.0f;
}

// ================= Stage 1: conv1d 512->512 k=3 as MFMA implicit GEMM ==============
// out[n][o][t] = bias[o] + sum_{i,k} w[o][i][k] * feat[n][i][t+k-1]
__global__ __launch_bounds__(256, 2) void k_conv1(const float* __restrict__ feat,
        const float* __restrict__ w, const float* __restrict__ bias, bf16* __restrict__ out){
    __shared__ __align__(16) short Ws[TM * RS];
    __shared__ __align__(16) short Ss[TN * RS];
    int t0 = blockIdx.x * TN, o0 = blockIdx.y * TM, n = blockIdx.z;
    int tid = threadIdx.x, wid = tid >> 6, lane = tid & 63;
    int quad = lane >> 4, l15 = lane & 15;
    const float* fbase = feat + (size_t)n * Cc * Tt;

    float4v acc[2][8];
    #pragma unroll
    for (int m = 0; m < 2; ++m)
        #pragma unroll
        for (int f = 0; f < 8; ++f) acc[m][f] = (float4v){0.f, 0.f, 0.f, 0.f};

    for (int ic = 0; ic < Cc; ic += KI){
        // stage W tile: [128 o][96 k] bf16 (fp32 global -> cvt -> LDS)
        for (int p = tid; p < TM * 24; p += 256){
            int o = p / 24, seg = p % 24;
            float4v wv = *reinterpret_cast<const float4v*>(
                &w[(size_t)(o0 + o) * (Cc * 3) + ic * 3 + seg * 4]);
            short4v s4 = { f2s(wv.x), f2s(wv.y), f2s(wv.z), f2s(wv.w) };
            *reinterpret_cast<short4v*>(&Ws[o * RS + seg * 4]) = s4;
        }
        // stage S tile: S[t][i*3+k] = feat[ic+i][t0+t+k-1] (0-pad at edges)
        for (int p = tid; p < KI * TN; p += 256){
            int t = p & (TN - 1), i = p >> 7;
            int tt = t0 + t;
            const float* fr = fbase + (size_t)(ic + i) * Tt;
            float xm = (tt >= 1)      ? fr[tt - 1] : 0.f;
            float x0 = fr[tt];
            float xp = (tt + 1 < Tt)  ? fr[tt + 1] : 0.f;
            short* d = &Ss[t * RS + i * 3];
            d[0] = f2s(xm); d[1] = f2s(x0); d[2] = f2s(xp);
        }
        __syncthreads();
        #pragma unroll
        for (int kk = 0; kk < KC; kk += 32){
            short8 a[2], b[8];
            #pragma unroll
            for (int m = 0; m < 2; ++m)
                a[m] = *reinterpret_cast<const short8*>(
                    &Ws[(wid * 32 + m * 16 + l15) * RS + kk + quad * 8]);
            #pragma unroll
            for (int f = 0; f < 8; ++f)
                b[f] = *reinterpret_cast<const short8*>(
                    &Ss[(f * 16 + l15) * RS + kk + quad * 8]);
            #pragma unroll
            for (int m = 0; m < 2; ++m)
                #pragma unroll
                for (int f = 0; f < 8; ++f)
                    acc[m][f] = __builtin_amdgcn_mfma_f32_16x16x32_bf16(a[m], b[f], acc[m][f], 0, 0, 0);
        }
        __syncthreads();
    }
    // epilogue: +bias, bf16 store. D map: row(o)=quad*4+reg, col(t)=lane&15
    bf16* ob = out + (size_t)n * Cc * Tt;
    #pragma unroll
    for (int m = 0; m < 2; ++m){
        int obase = o0 + wid * 32 + m * 16 + quad * 4;
        #pragma unroll
        for (int r = 0; r < 4; ++r){
            float bs = bias[obase + r];
            size_t row = (size_t)(obase + r) * Tt;
            #pragma unroll
            for (int f = 0; f < 8; ++f)
                ob[row + t0 + f * 16 + l15] = f2b(acc[m][f][r] + bs);
        }
    }
}

// ================= Stage 2: group-norm =================
__global__ void k_gnstats(const bf16* __restrict__ x, float* __restrict__ mean,
                          float* __restrict__ rstd){
    int blk = blockIdx.x;
    const bf16* base = x + (size_t)blk * CPG * Tt;
    float s = 0.f, ss = 0.f;
    for (int j = threadIdx.x; j < CPG * Tt; j += 256){
        float v = b2f(base[j]); s += v; ss += v * v;
    }
    __shared__ float sh[512];
    sh[threadIdx.x] = s; sh[256 + threadIdx.x] = ss;
    __syncthreads();
    for (int off = 128; off > 0; off >>= 1){
        if (threadIdx.x < off){
            sh[threadIdx.x] += sh[threadIdx.x + off];
            sh[256 + threadIdx.x] += sh[256 + threadIdx.x + off];
        }
        __syncthreads();
    }
    if (threadIdx.x == 0){
        float m = sh[0] / (float)(CPG * Tt);
        float v = sh[256] / (float)(CPG * Tt) - m * m;
        mean[blk] = m; rstd[blk] = rsqrtf(v + EPS);
    }
}

__global__ void k_gnapply(bf16* __restrict__ x, const float* __restrict__ mean,
                          const float* __restrict__ rstd, const float* __restrict__ gamma,
                          const float* __restrict__ beta){
    int idx = blockIdx.x * 256 + threadIdx.x;
    int c = (idx >> 12) & (Cc - 1);
    int n = idx >> 21;
    int blk = n * Gg + (c / CPG);
    float v = (b2f(x[idx]) - mean[blk]) * rstd[blk] * gamma[c] + beta[c];
    x[idx] = f2b(fmaxf(v, 0.f));
}

// ================= Stage 3: deformable conv as MFMA implicit GEMM =================
__global__ __launch_bounds__(256, 2) void k_deform(const bf16* __restrict__ h,
        const float* __restrict__ locs, const float* __restrict__ w,
        const float* __restrict__ bias, const void* __restrict__ sp,
        float* __restrict__ out){
    __shared__ __align__(16) short Ws[TM * RS];
    __shared__ __align__(16) short Ss[TN * RS];
    __shared__ float wa0[TN], wa1[TN], wc0[TN], wc1[TN];
    __shared__ int   ia0[TN], ia1[TN], ic0[TN], ic1[TN];
    int t0 = blockIdx.x * TN, o0 = blockIdx.y * TM, n = blockIdx.z;
    int tid = threadIdx.x, wid = tid >> 6, lane = tid & 63;
    int quad = lane >> 4, l15 = lane & 15;

    if (tid < TN){
        int tt = t0 + tid;
        float s = stride_val(sp);
        float l1 = locs[((size_t)n * 2 + 0) * Tt + tt];
        float l2 = locs[((size_t)n * 2 + 1) * Tt + tt];
        float y1 = (0.9f * l1 + 0.1f * l1) / s;   // match ref's GRAD_MUL arithmetic
        float y2 = (0.9f * l2 + 0.1f * l2) / s;
        float pos0 = (float)(tt - 1) - y1;
        float pos2 = (float)(tt + 1) + y2;
        float p0f = floorf(pos0), p2f = floorf(pos2);
        float w1 = pos0 - p0f, w2 = pos2 - p2f;
        int a0 = (int)p0f, a1 = a0 + 1, c0 = (int)p2f, c1 = c0 + 1;
        wa0[tid] = (a0 >= 0 && a0 < Tt) ? (1.f - w1) : 0.f;
        wa1[tid] = (a1 >= 0 && a1 < Tt) ? w1 : 0.f;
        wc0[tid] = (c0 >= 0 && c0 < Tt) ? (1.f - w2) : 0.f;
        wc1[tid] = (c1 >= 0 && c1 < Tt) ? w2 : 0.f;
        ia0[tid] = min(max(a0, 0), Tt - 1);
        ia1[tid] = min(max(a1, 0), Tt - 1);
        ic0[tid] = min(max(c0, 0), Tt - 1);
        ic1[tid] = min(max(c1, 0), Tt - 1);
    }
    __syncthreads();

    float4v acc[2][8];
    #pragma unroll
    for (int m = 0; m < 2; ++m)
        #pragma unroll
        for (int f = 0; f < 8; ++f) acc[m][f] = (float4v){0.f, 0.f, 0.f, 0.f};

    for (int ic = 0; ic < Cc; ic += KI){
        for (int p = tid; p < TM * 24; p += 256){
            int o = p / 24, seg = p % 24;
            float4v wv = *reinterpret_cast<const float4v*>(
                &w[(size_t)(o0 + o) * (Cc * 3) + ic * 3 + seg * 4]);
            short4v s4 = { f2s(wv.x), f2s(wv.y), f2s(wv.z), f2s(wv.w) };
            *reinterpret_cast<short4v*>(&Ws[o * RS + seg * 4]) = s4;
        }
        for (int p = tid; p < KI * TN; p += 256){
            int t = p & (TN - 1), i = p >> 7;
            const bf16* hr = h + ((size_t)n * Cc + (ic + i)) * Tt;
            float s00 = b2f(hr[ia0[t]]);
            float s01 = b2f(hr[ia1[t]]);
            float s20 = b2f(hr[ic0[t]]);
            float s21 = b2f(hr[ic1[t]]);
            short* d = &Ss[t * RS + i * 3];
            d[0] = f2s(s00 * wa0[t] + s01 * wa1[t]);
            d[1] = ((const short*)hr)[t0 + t];       // k=1 tap: exact integer position
            d[2] = f2s(s20 * wc0[t] + s21 * wc1[t]);
        }
        __syncthreads();
        #pragma unroll
        for (int kk = 0; kk < KC; kk += 32){
            short8 a[2], b[8];
            #pragma unroll
            for (int m = 0; m < 2; ++m)
                a[m] = *reinterpret_cast<const short8*>(
                    &Ws[(wid * 32 + m * 16 + l15) * RS + kk + quad * 8]);
            #pragma unroll
            for (int f = 0; f < 8; ++f)
                b[f] = *reinterpret_cast<const short8*>(
                    &Ss[(f * 16 + l15) * RS + kk + quad * 8]);
            #pragma unroll
            for (int m = 0; m < 2; ++m)
                #pragma unroll
                for (int f = 0; f < 8; ++f)
                    acc[m][f] = __builtin_amdgcn_mfma_f32_16x16x32_bf16(a[m], b[f], acc[m][f], 0, 0, 0);
        }
        __syncthreads();
    }
    // epilogue: +bias, relu, fp32 store
    float* ob = out + (size_t)n * Cc * Tt;
    #pragma unroll
    for (int m = 0; m < 2; ++m){
        int obase = o0 + wid * 32 + m * 16 + quad * 4;
        #pragma unroll
        for (int r = 0; r < 4; ++r){
            float bs = bias[obase + r];
            size_t row = (size_t)(obase + r) * Tt;
            #pragma unroll
            for (int f = 0; f < 8; ++f)
                ob[row + t0 + f * 16 + l15] = fmaxf(acc[m][f][r] + bs, 0.f);
        }
    }
}

// ================= Stage 4: conv1d 512->2, K-split + atomics =================
__global__ void k_outinit(const float* __restrict__ ob, float* __restrict__ out){
    int idx = blockIdx.x * 256 + threadIdx.x;      // 65536
    out[idx] = ob[(idx >> 12) & 1];
}

__global__ void k_outconv(const float* __restrict__ x, const float* __restrict__ w,
                          float* __restrict__ out){
    int t  = blockIdx.x * 256 + threadIdx.x;       // 0..4095
    int i0 = blockIdx.y * 64;
    int n  = blockIdx.z;
    const float* xb = x + (size_t)n * Cc * Tt;
    float a0 = 0.f, a1 = 0.f;
    bool tm = (t > 0), tp = (t < Tt - 1);
    for (int i = i0; i < i0 + 64; ++i){
        const float* xr = xb + (size_t)i * Tt + t;
        float xm = tm ? xr[-1] : 0.f;
        float x0 = xr[0];
        float xp = tp ? xr[1] : 0.f;
        const float* w0 = w + i * 3;
        const float* w1 = w + Cc * 3 + i * 3;
        a0 += xm * w0[0] + x0 * w0[1] + xp * w0[2];
        a1 += xm * w1[0] + x0 * w1[1] + xp * w1[2];
    }
    atomicAdd(&out[((size_t)n * 2 + 0) * Tt + t], a0);
    atomicAdd(&out[((size_t)n * 2 + 1) * Tt + t], a1);
}

// ================= host =================
extern "C" void kernel_launch(void* const* d_in, const int* in_sizes, int n_in,
                              void* d_out, int out_size, void* d_ws, size_t ws_size,
                              hipStream_t stream) {
    const float* feat   = (const float*)d_in[0];
    const float* locs   = (const float*)d_in[1];
    const float* conv_w = (const float*)d_in[2];
    const float* conv_b = (const float*)d_in[3];
    const float* gn_g   = (const float*)d_in[4];
    const float* gn_b   = (const float*)d_in[5];
    const float* dcn_w  = (const float*)d_in[6];
    const float* dcn_b  = (const float*)d_in[7];
    const float* out_w  = (const float*)d_in[8];
    const float* out_b  = (const float*)d_in[9];

    float* offset      = (float*)d_out;                        // (8,2,4096) fp32
    float* offset_feat = (float*)d_out + (size_t)Nn * 2 * Tt;  // (8,512,4096) fp32

    float* mean = (float*)d_ws;
    float* rstd = mean + 256;
    bf16*  h    = (bf16*)((char*)d_ws + 4096);                 // 32 MB bf16

    dim3 gemm_grid(Tt / TN, Cc / TM, Nn);                      // (32,4,8)

    k_conv1  <<<gemm_grid, 256, 0, stream>>>(feat, conv_w, conv_b, h);
    k_gnstats<<<Nn * Gg, 256, 0, stream>>>(h, mean, rstd);
    k_gnapply<<<(Nn * Cc * Tt) / 256, 256, 0, stream>>>(h, mean, rstd, gn_g, gn_b);
    k_deform <<<gemm_grid, 256, 0, stream>>>(h, locs, dcn_w, dcn_b, d_in[10], offset_feat);
    k_outinit<<<(Nn * 2 * Tt) / 256, 256, 0, stream>>>(out_b, offset);
    k_outconv<<<dim3(Tt / 256, Cc / 64, Nn), 256, 0, stream>>>(offset_feat, out_w, offset);
}

// Round 6
// 660.044 us; speedup vs baseline: 38.4672x; 1.5968x over previous
//
#include <hip/hip_runtime.h>
#include <hip/hip_bf16.h>

typedef __hip_bfloat16 bf16;
typedef __attribute__((ext_vector_type(8))) short short8;
typedef __attribute__((ext_vector_type(4))) short short4v;
typedef __attribute__((ext_vector_type(4))) float float4v;

constexpr int Nn = 8, Cc = 512, Tt = 4096, Gg = 32, CPG = 16;
constexpr float EPS = 1e-5f;

__device__ __forceinline__ float b2f(bf16 x){ return __bfloat162float(x); }
__device__ __forceinline__ bf16  f2b(float x){ return __float2bfloat16(x); }
__device__ __forceinline__ short f2s(float x){
    union { bf16 b; short s; } u; u.b = f2b(x); return u.s;
}
__device__ __forceinline__ float s2f(short x){
    union { short s; bf16 b; } u; u.s = x; return b2f(u.b);
}

__device__ __forceinline__ float stride_val(const void* sp){
    int si = *(const int*)sp;
    if (si >= 1 && si <= 100000) return (float)si;
    float sf = *(const float*)sp;
    if (sf >= 0.5f && sf <= 1.0e5f) return sf;
    return 8.0f;
}

// =====================================================================
// ============================ FAST PATH ==============================
// =====================================================================

// ---- P1: transpose feat fp32 [n][i][t] -> ftr bf16 [n][t+1][i] (pad rows 0,4097) ----
__global__ void k_transpose(const float* __restrict__ feat, bf16* __restrict__ ftr){
    __shared__ float L[64 * 65];
    int t0 = blockIdx.x * 64, i0 = blockIdx.y * 64, n = blockIdx.z;
    int tid = threadIdx.x;
    const float* fb = feat + ((size_t)n * Cc + i0) * Tt + t0;
    #pragma unroll
    for (int it = 0; it < 4; ++it){
        int p = tid + it * 256;
        int i = p >> 4, t4 = (p & 15) * 4;
        float4v v = *(const float4v*)&fb[(size_t)i * Tt + t4];
        L[(t4 + 0) * 65 + i] = v.x;
        L[(t4 + 1) * 65 + i] = v.y;
        L[(t4 + 2) * 65 + i] = v.z;
        L[(t4 + 3) * 65 + i] = v.w;
    }
    __syncthreads();
    #pragma unroll
    for (int it = 0; it < 2; ++it){
        int p = tid + it * 256;
        int t = p >> 3, s = p & 7;
        short8 sv;
        #pragma unroll
        for (int j = 0; j < 8; ++j) sv[j] = f2s(L[t * 65 + s * 8 + j]);
        *(short8*)&ftr[((size_t)n * 4098 + t0 + t + 1) * Cc + i0 + s * 8] = sv;
    }
}

__global__ void k_zpad(bf16* __restrict__ ftr){
    int p = blockIdx.x * 256 + threadIdx.x;      // 8192
    int n = p >> 10, r = (p >> 9) & 1, i = p & 511;
    ftr[((size_t)n * 4098 + (r ? 4097 : 0)) * Cc + i] = f2b(0.f);
}

// ---- P2: weights fp32 [o][i][k] -> bf16 [k][o][i] ----
__global__ void k_wcvt(const float* __restrict__ w, bf16* __restrict__ wt){
    int p = blockIdx.x * 256 + threadIdx.x;      // 786432
    int k = p >> 18, rest = p & 262143;
    wt[p] = f2b(w[(size_t)rest * 3 + k]);
}

// ---- conv1 as no-LDS MFMA GEMM; output transposed to ht[n][t][o] via LDS epilogue ----
__global__ __launch_bounds__(256, 2) void k_conv1g(const bf16* __restrict__ ftr,
        const bf16* __restrict__ wtc, const float* __restrict__ bias, bf16* __restrict__ ht){
    __shared__ float Lt[64 * 129];
    int t0 = blockIdx.x * 128, o0 = blockIdx.y * 128, n = blockIdx.z;
    int tid = threadIdx.x, wid = tid >> 6, lane = tid & 63;
    int quad = lane >> 4, l15 = lane & 15;
    float4v acc[2][8];
    #pragma unroll
    for (int m = 0; m < 2; ++m)
        #pragma unroll
        for (int f = 0; f < 8; ++f) acc[m][f] = (float4v){0.f,0.f,0.f,0.f};

    const bf16* fb  = ftr + (size_t)n * 4098 * Cc + ((size_t)(t0 + l15)) * Cc + quad * 8;
    const bf16* wb0 = wtc + ((size_t)(o0 + wid * 32 + l15)) * Cc + quad * 8;

    for (int ic = 0; ic < Cc; ic += 32){
        #pragma unroll
        for (int tap = 0; tap < 3; ++tap){
            const bf16* wp = wb0 + (size_t)tap * 262144 + ic;
            short8 a0 = *(const short8*)wp;
            short8 a1 = *(const short8*)(wp + 8192);          // +16 o rows
            const bf16* bp = fb + (size_t)tap * Cc + ic;
            #pragma unroll
            for (int f = 0; f < 8; ++f){
                short8 b = *(const short8*)(bp + (size_t)f * 8192);  // +16 t rows
                acc[0][f] = __builtin_amdgcn_mfma_f32_16x16x32_bf16(a0, b, acc[0][f], 0, 0, 0);
                acc[1][f] = __builtin_amdgcn_mfma_f32_16x16x32_bf16(a1, b, acc[1][f], 0, 0, 0);
            }
        }
    }
    // epilogue: +bias, transpose [o][t]->[t][o] through LDS, bf16 store
    int ol = wid * 32 + quad * 4;
    #pragma unroll
    for (int pass = 0; pass < 2; ++pass){
        __syncthreads();
        #pragma unroll
        for (int m = 0; m < 2; ++m){
            #pragma unroll
            for (int ff = 0; ff < 4; ++ff){
                int fr = pass * 4 + ff;
                int tl = ff * 16 + l15;
                #pragma unroll
                for (int r = 0; r < 4; ++r)
                    Lt[tl * 129 + ol + m * 16 + r] = acc[m][fr][r] + bias[o0 + ol + m * 16 + r];
            }
        }
        __syncthreads();
        #pragma unroll
        for (int it = 0; it < 4; ++it){
            int p = tid + it * 256;
            int tl = p >> 4, s = p & 15;
            short8 sv;
            #pragma unroll
            for (int j = 0; j < 8; ++j) sv[j] = f2s(Lt[tl * 129 + s * 8 + j]);
            *(short8*)&ht[((size_t)n * Tt + t0 + pass * 64 + tl) * Cc + o0 + s * 8] = sv;
        }
    }
}

// ---- GN stats on ht[n][t][i] : block per (n,g) ----
__global__ void k_gnstats2(const bf16* __restrict__ ht, float* __restrict__ mean,
                           float* __restrict__ rstd){
    int blk = blockIdx.x;                  // n*32+g
    int n = blk >> 5, g = blk & 31;
    const bf16* base = ht + (size_t)n * Tt * Cc + g * 16 + (threadIdx.x & 1) * 8;
    float s = 0.f, ss = 0.f;
    for (int r = threadIdx.x >> 1; r < Tt; r += 128){
        short8 v = *(const short8*)&base[(size_t)r * Cc];
        #pragma unroll
        for (int j = 0; j < 8; ++j){ float f = s2f(v[j]); s += f; ss += f * f; }
    }
    __shared__ float sh[512];
    sh[threadIdx.x] = s; sh[256 + threadIdx.x] = ss;
    __syncthreads();
    for (int off = 128; off > 0; off >>= 1){
        if (threadIdx.x < off){
            sh[threadIdx.x] += sh[threadIdx.x + off];
            sh[256 + threadIdx.x] += sh[256 + threadIdx.x + off];
        }
        __syncthreads();
    }
    if (threadIdx.x == 0){
        float m = sh[0] / (float)(CPG * Tt);
        float v = sh[256] / (float)(CPG * Tt) - m * m;
        mean[blk] = m; rstd[blk] = rsqrtf(v + EPS);
    }
}

// ---- GN apply + relu, in place on ht ----
__global__ void k_gnapply2(bf16* __restrict__ ht, const float* __restrict__ mean,
        const float* __restrict__ rstd, const float* __restrict__ gamma,
        const float* __restrict__ beta){
    int p = blockIdx.x * 256 + threadIdx.x;   // 2,097,152 short8 slots
    int s = p & 63, row = p >> 6;             // row = n*4096+t
    int n = row >> 12;
    int ib = s * 8;
    int blk = n * 32 + (ib >> 4);
    float mu = mean[blk], rs = rstd[blk];
    short8 v = *(short8*)&ht[(size_t)row * Cc + ib];
    short8 o;
    #pragma unroll
    for (int j = 0; j < 8; ++j){
        int c = ib + j;
        float f = (s2f(v[j]) - mu) * rs * gamma[c] + beta[c];
        o[j] = f2s(fmaxf(f, 0.f));
    }
    *(short8*)&ht[(size_t)row * Cc + ib] = o;
}

// ---- per-(n,t) deform sampling params ----
__global__ void k_prep(const float* __restrict__ locs, const void* __restrict__ sp,
        int* __restrict__ ia0, int* __restrict__ ia1, int* __restrict__ ic0,
        int* __restrict__ ic1, float* __restrict__ wa0, float* __restrict__ wa1,
        float* __restrict__ wc0, float* __restrict__ wc1){
    int idx = blockIdx.x * 256 + threadIdx.x;   // 32768
    int t = idx & 4095, n = idx >> 12;
    float s = stride_val(sp);
    float l1 = locs[((size_t)n * 2 + 0) * Tt + t];
    float l2 = locs[((size_t)n * 2 + 1) * Tt + t];
    float y1 = (0.9f * l1 + 0.1f * l1) / s;     // match ref GRAD_MUL arithmetic
    float y2 = (0.9f * l2 + 0.1f * l2) / s;
    float pos0 = (float)(t - 1) - y1;
    float pos2 = (float)(t + 1) + y2;
    float p0f = floorf(pos0), p2f = floorf(pos2);
    float w1 = pos0 - p0f, w2 = pos2 - p2f;
    int a0 = (int)p0f, a1 = a0 + 1, c0 = (int)p2f, c1 = c0 + 1;
    wa0[idx] = (a0 >= 0 && a0 < Tt) ? (1.f - w1) : 0.f;
    wa1[idx] = (a1 >= 0 && a1 < Tt) ? w1 : 0.f;
    wc0[idx] = (c0 >= 0 && c0 < Tt) ? (1.f - w2) : 0.f;
    wc1[idx] = (c1 >= 0 && c1 < Tt) ? w2 : 0.f;
    ia0[idx] = min(max(a0, 0), Tt - 1);
    ia1[idx] = min(max(a1, 0), Tt - 1);
    ic0[idx] = min(max(c0, 0), Tt - 1);
    ic1[idx] = min(max(c1, 0), Tt - 1);
}

// ---- materialize S0t/S2t (gather+lerp, coalesced in i) ----
__global__ void k_sample(const bf16* __restrict__ ht, const int* __restrict__ ia0,
        const int* __restrict__ ia1, const int* __restrict__ ic0, const int* __restrict__ ic1,
        const float* __restrict__ wa0, const float* __restrict__ wa1,
        const float* __restrict__ wc0, const float* __restrict__ wc1,
        bf16* __restrict__ S0, bf16* __restrict__ S2){
    int n = blockIdx.y;
    int t0 = blockIdx.x * 16;
    int lane = threadIdx.x & 63, slot = threadIdx.x >> 6;
    const bf16* hb = ht + (size_t)n * Tt * Cc;
    #pragma unroll
    for (int rr = 0; rr < 4; ++rr){
        int t = t0 + slot * 4 + rr;
        int idx = n * Tt + t;
        {
            short8 lo = *(const short8*)&hb[(size_t)ia0[idx] * Cc + lane * 8];
            short8 hi = *(const short8*)&hb[(size_t)ia1[idx] * Cc + lane * 8];
            float w0 = wa0[idx], w1 = wa1[idx];
            short8 o;
            #pragma unroll
            for (int j = 0; j < 8; ++j) o[j] = f2s(w0 * s2f(lo[j]) + w1 * s2f(hi[j]));
            *(short8*)&S0[(size_t)idx * Cc + lane * 8] = o;
        }
        {
            short8 lo = *(const short8*)&hb[(size_t)ic0[idx] * Cc + lane * 8];
            short8 hi = *(const short8*)&hb[(size_t)ic1[idx] * Cc + lane * 8];
            float w0 = wc0[idx], w1 = wc1[idx];
            short8 o;
            #pragma unroll
            for (int j = 0; j < 8; ++j) o[j] = f2s(w0 * s2f(lo[j]) + w1 * s2f(hi[j]));
            *(short8*)&S2[(size_t)idx * Cc + lane * 8] = o;
        }
    }
}

// ---- deform as no-LDS MFMA GEMM over 3 B-buffers; fp32 out [n][o][t] ----
__global__ __launch_bounds__(256, 2) void k_deformg(const bf16* __restrict__ S0,
        const bf16* __restrict__ ht, const bf16* __restrict__ S2,
        const bf16* __restrict__ wtd, const float* __restrict__ bias,
        float* __restrict__ out){
    int t0 = blockIdx.x * 128, o0 = blockIdx.y * 128, n = blockIdx.z;
    int tid = threadIdx.x, wid = tid >> 6, lane = tid & 63;
    int quad = lane >> 4, l15 = lane & 15;
    float4v acc[2][8];
    #pragma unroll
    for (int m = 0; m < 2; ++m)
        #pragma unroll
        for (int f = 0; f < 8; ++f) acc[m][f] = (float4v){0.f,0.f,0.f,0.f};

    size_t rowoff = ((size_t)n * Tt + t0 + l15) * Cc + quad * 8;
    const bf16* bases[3] = { S0 + rowoff, ht + rowoff, S2 + rowoff };
    const bf16* wb0 = wtd + ((size_t)(o0 + wid * 32 + l15)) * Cc + quad * 8;

    for (int ic = 0; ic < Cc; ic += 32){
        #pragma unroll
        for (int tap = 0; tap < 3; ++tap){
            const bf16* wp = wb0 + (size_t)tap * 262144 + ic;
            short8 a0 = *(const short8*)wp;
            short8 a1 = *(const short8*)(wp + 8192);
            const bf16* bp = bases[tap] + ic;
            #pragma unroll
            for (int f = 0; f < 8; ++f){
                short8 b = *(const short8*)(bp + (size_t)f * 8192);
                acc[0][f] = __builtin_amdgcn_mfma_f32_16x16x32_bf16(a0, b, acc[0][f], 0, 0, 0);
                acc[1][f] = __builtin_amdgcn_mfma_f32_16x16x32_bf16(a1, b, acc[1][f], 0, 0, 0);
            }
        }
    }
    float* ob = out + (size_t)n * Cc * Tt;
    #pragma unroll
    for (int m = 0; m < 2; ++m){
        int ob0 = o0 + wid * 32 + m * 16 + quad * 4;
        #pragma unroll
        for (int r = 0; r < 4; ++r){
            float bs = bias[ob0 + r];
            size_t row = (size_t)(ob0 + r) * Tt;
            #pragma unroll
            for (int f = 0; f < 8; ++f)
                ob[row + t0 + f * 16 + l15] = fmaxf(acc[m][f][r] + bs, 0.f);
        }
    }
}

// ---- Stage 4: conv1d 512->2, K-split + atomics (shared by both paths) ----
__global__ void k_outinit(const float* __restrict__ ob, float* __restrict__ out){
    int idx = blockIdx.x * 256 + threadIdx.x;      // 65536
    out[idx] = ob[(idx >> 12) & 1];
}

__global__ void k_outconv(const float* __restrict__ x, const float* __restrict__ w,
                          float* __restrict__ out){
    int t  = blockIdx.x * 256 + threadIdx.x;
    int i0 = blockIdx.y * 64;
    int n  = blockIdx.z;
    const float* xb = x + (size_t)n * Cc * Tt;
    float a0 = 0.f, a1 = 0.f;
    bool tm = (t > 0), tp = (t < Tt - 1);
    for (int i = i0; i < i0 + 64; ++i){
        const float* xr = xb + (size_t)i * Tt + t;
        float xm = tm ? xr[-1] : 0.f;
        float x0 = xr[0];
        float xp = tp ? xr[1] : 0.f;
        const float* w0 = w + i * 3;
        const float* w1 = w + Cc * 3 + i * 3;
        a0 += xm * w0[0] + x0 * w0[1] + xp * w0[2];
        a1 += xm * w1[0] + x0 * w1[1] + xp * w1[2];
    }
    atomicAdd(&out[((size_t)n * 2 + 0) * Tt + t], a0);
    atomicAdd(&out[((size_t)n * 2 + 1) * Tt + t], a1);
}

// =====================================================================
// ====================== FALLBACK (round-5 proven) ====================
// =====================================================================
constexpr int TM = 128, TN = 128, KI = 32, KC = 96, RS = 104;

__global__ __launch_bounds__(256, 2) void k_conv1_fb(const float* __restrict__ feat,
        const float* __restrict__ w, const float* __restrict__ bias, bf16* __restrict__ out){
    __shared__ __align__(16) short Ws[TM * RS];
    __shared__ __align__(16) short Ss[TN * RS];
    int t0 = blockIdx.x * TN, o0 = blockIdx.y * TM, n = blockIdx.z;
    int tid = threadIdx.x, wid = tid >> 6, lane = tid & 63;
    int quad = lane >> 4, l15 = lane & 15;
    const float* fbase = feat + (size_t)n * Cc * Tt;
    float4v acc[2][8];
    #pragma unroll
    for (int m = 0; m < 2; ++m)
        #pragma unroll
        for (int f = 0; f < 8; ++f) acc[m][f] = (float4v){0.f,0.f,0.f,0.f};
    for (int ic = 0; ic < Cc; ic += KI){
        for (int p = tid; p < TM * 24; p += 256){
            int o = p / 24, seg = p % 24;
            float4v wv = *reinterpret_cast<const float4v*>(
                &w[(size_t)(o0 + o) * (Cc * 3) + ic * 3 + seg * 4]);
            short4v s4 = { f2s(wv.x), f2s(wv.y), f2s(wv.z), f2s(wv.w) };
            *reinterpret_cast<short4v*>(&Ws[o * RS + seg * 4]) = s4;
        }
        for (int p = tid; p < KI * TN; p += 256){
            int t = p & (TN - 1), i = p >> 7;
            int tt = t0 + t;
            const float* fr = fbase + (size_t)(ic + i) * Tt;
            float xm = (tt >= 1) ? fr[tt - 1] : 0.f;
            float x0 = fr[tt];
            float xp = (tt + 1 < Tt) ? fr[tt + 1] : 0.f;
            short* d = &Ss[t * RS + i * 3];
            d[0] = f2s(xm); d[1] = f2s(x0); d[2] = f2s(xp);
        }
        __syncthreads();
        #pragma unroll
        for (int kk = 0; kk < KC; kk += 32){
            short8 a[2], b[8];
            #pragma unroll
            for (int m = 0; m < 2; ++m)
                a[m] = *reinterpret_cast<const short8*>(&Ws[(wid*32 + m*16 + l15)*RS + kk + quad*8]);
            #pragma unroll
            for (int f = 0; f < 8; ++f)
                b[f] = *reinterpret_cast<const short8*>(&Ss[(f*16 + l15)*RS + kk + quad*8]);
            #pragma unroll
            for (int m = 0; m < 2; ++m)
                #pragma unroll
                for (int f = 0; f < 8; ++f)
                    acc[m][f] = __builtin_amdgcn_mfma_f32_16x16x32_bf16(a[m], b[f], acc[m][f], 0, 0, 0);
        }
        __syncthreads();
    }
    bf16* ob = out + (size_t)n * Cc * Tt;
    #pragma unroll
    for (int m = 0; m < 2; ++m){
        int obase = o0 + wid * 32 + m * 16 + quad * 4;
        #pragma unroll
        for (int r = 0; r < 4; ++r){
            float bs = bias[obase + r];
            size_t row = (size_t)(obase + r) * Tt;
            #pragma unroll
            for (int f = 0; f < 8; ++f)
                ob[row + t0 + f * 16 + l15] = f2b(acc[m][f][r] + bs);
        }
    }
}

__global__ void k_gnstats_fb(const bf16* __restrict__ x, float* __restrict__ mean,
                             float* __restrict__ rstd){
    int blk = blockIdx.x;
    const bf16* base = x + (size_t)blk * CPG * Tt;
    float s = 0.f, ss = 0.f;
    for (int j = threadIdx.x; j < CPG * Tt; j += 256){
        float v = b2f(base[j]); s += v; ss += v * v;
    }
    __shared__ float sh[512];
    sh[threadIdx.x] = s; sh[256 + threadIdx.x] = ss;
    __syncthreads();
    for (int off = 128; off > 0; off >>= 1){
        if (threadIdx.x < off){
            sh[threadIdx.x] += sh[threadIdx.x + off];
            sh[256 + threadIdx.x] += sh[256 + threadIdx.x + off];
        }
        __syncthreads();
    }
    if (threadIdx.x == 0){
        float m = sh[0] / (float)(CPG * Tt);
        float v = sh[256] / (float)(CPG * Tt) - m * m;
        mean[blk] = m; rstd[blk] = rsqrtf(v + EPS);
    }
}

__global__ void k_gnapply_fb(bf16* __restrict__ x, const float* __restrict__ mean,
        const float* __restrict__ rstd, const float* __restrict__ gamma,
        const float* __restrict__ beta){
    int idx = blockIdx.x * 256 + threadIdx.x;
    int c = (idx >> 12) & (Cc - 1);
    int n = idx >> 21;
    int blk = n * Gg + (c / CPG);
    float v = (b2f(x[idx]) - mean[blk]) * rstd[blk] * gamma[c] + beta[c];
    x[idx] = f2b(fmaxf(v, 0.f));
}

__global__ __launch_bounds__(256, 2) void k_deform_fb(const bf16* __restrict__ h,
        const float* __restrict__ locs, const float* __restrict__ w,
        const float* __restrict__ bias, const void* __restrict__ sp,
        float* __restrict__ out){
    __shared__ __align__(16) short Ws[TM * RS];
    __shared__ __align__(16) short Ss[TN * RS];
    __shared__ float wa0[TN], wa1[TN], wc0[TN], wc1[TN];
    __shared__ int   ia0[TN], ia1[TN], ic0[TN], ic1[TN];
    int t0 = blockIdx.x * TN, o0 = blockIdx.y * TM, n = blockIdx.z;
    int tid = threadIdx.x, wid = tid >> 6, lane = tid & 63;
    int quad = lane >> 4, l15 = lane & 15;
    if (tid < TN){
        int tt = t0 + tid;
        float s = stride_val(sp);
        float l1 = locs[((size_t)n * 2 + 0) * Tt + tt];
        float l2 = locs[((size_t)n * 2 + 1) * Tt + tt];
        float y1 = (0.9f * l1 + 0.1f * l1) / s;
        float y2 = (0.9f * l2 + 0.1f * l2) / s;
        float pos0 = (float)(tt - 1) - y1;
        float pos2 = (float)(tt + 1) + y2;
        float p0f = floorf(pos0), p2f = floorf(pos2);
        float w1 = pos0 - p0f, w2 = pos2 - p2f;
        int a0 = (int)p0f, a1 = a0 + 1, c0 = (int)p2f, c1 = c0 + 1;
        wa0[tid] = (a0 >= 0 && a0 < Tt) ? (1.f - w1) : 0.f;
        wa1[tid] = (a1 >= 0 && a1 < Tt) ? w1 : 0.f;
        wc0[tid] = (c0 >= 0 && c0 < Tt) ? (1.f - w2) : 0.f;
        wc1[tid] = (c1 >= 0 && c1 < Tt) ? w2 : 0.f;
        ia0[tid] = min(max(a0, 0), Tt - 1);
        ia1[tid] = min(max(a1, 0), Tt - 1);
        ic0[tid] = min(max(c0, 0), Tt - 1);
        ic1[tid] = min(max(c1, 0), Tt - 1);
    }
    __syncthreads();
    float4v acc[2][8];
    #pragma unroll
    for (int m = 0; m < 2; ++m)
        #pragma unroll
        for (int f = 0; f < 8; ++f) acc[m][f] = (float4v){0.f,0.f,0.f,0.f};
    for (int ic = 0; ic < Cc; ic += KI){
        for (int p = tid; p < TM * 24; p += 256){
            int o = p / 24, seg = p % 24;
            float4v wv = *reinterpret_cast<const float4v*>(
                &w[(size_t)(o0 + o) * (Cc * 3) + ic * 3 + seg * 4]);
            short4v s4 = { f2s(wv.x), f2s(wv.y), f2s(wv.z), f2s(wv.w) };
            *reinterpret_cast<short4v*>(&Ws[o * RS + seg * 4]) = s4;
        }
        for (int p = tid; p < KI * TN; p += 256){
            int t = p & (TN - 1), i = p >> 7;
            const bf16* hr = h + ((size_t)n * Cc + (ic + i)) * Tt;
            float s00 = b2f(hr[ia0[t]]);
            float s01 = b2f(hr[ia1[t]]);
            float s20 = b2f(hr[ic0[t]]);
            float s21 = b2f(hr[ic1[t]]);
            short* d = &Ss[t * RS + i * 3];
            d[0] = f2s(s00 * wa0[t] + s01 * wa1[t]);
            d[1] = ((const short*)hr)[t0 + t];
            d[2] = f2s(s20 * wc0[t] + s21 * wc1[t]);
        }
        __syncthreads();
        #pragma unroll
        for (int kk = 0; kk < KC; kk += 32){
            short8 a[2], b[8];
            #pragma unroll
            for (int m = 0; m < 2; ++m)
                a[m] = *reinterpret_cast<const short8*>(&Ws[(wid*32 + m*16 + l15)*RS + kk + quad*8]);
            #pragma unroll
            for (int f = 0; f < 8; ++f)
                b[f] = *reinterpret_cast<const short8*>(&Ss[(f*16 + l15)*RS + kk + quad*8]);
            #pragma unroll
            for (int m = 0; m < 2; ++m)
                #pragma unroll
                for (int f = 0; f < 8; ++f)
                    acc[m][f] = __builtin_amdgcn_mfma_f32_16x16x32_bf16(a[m], b[f], acc[m][f], 0, 0, 0);
        }
        __syncthreads();
    }
    float* ob = out + (size_t)n * Cc * Tt;
    #pragma unroll
    for (int m = 0; m < 2; ++m){
        int obase = o0 + wid * 32 + m * 16 + quad * 4;
        #pragma unroll
        for (int r = 0; r < 4; ++r){
            float bs = bias[obase + r];
            size_t row = (size_t)(obase + r) * Tt;
            #pragma unroll
            for (int f = 0; f < 8; ++f)
                ob[row + t0 + f * 16 + l15] = fmaxf(acc[m][f][r] + bs, 0.f);
        }
    }
}

// =====================================================================
// ============================== HOST =================================
// =====================================================================
extern "C" void kernel_launch(void* const* d_in, const int* in_sizes, int n_in,
                              void* d_out, int out_size, void* d_ws, size_t ws_size,
                              hipStream_t stream) {
    const float* feat   = (const float*)d_in[0];
    const float* locs   = (const float*)d_in[1];
    const float* conv_w = (const float*)d_in[2];
    const float* conv_b = (const float*)d_in[3];
    const float* gn_g   = (const float*)d_in[4];
    const float* gn_b   = (const float*)d_in[5];
    const float* dcn_w  = (const float*)d_in[6];
    const float* dcn_b  = (const float*)d_in[7];
    const float* out_w  = (const float*)d_in[8];
    const float* out_b  = (const float*)d_in[9];

    float* offset      = (float*)d_out;                        // (8,2,4096) fp32
    float* offset_feat = (float*)d_out + (size_t)Nn * 2 * Tt;  // (8,512,4096) fp32

    constexpr size_t SZ_PREP = 32768 * 4;
    constexpr size_t OFF_PREP = 4096;
    constexpr size_t OFF_WTC  = OFF_PREP + 8 * SZ_PREP;                 // 1,052,672
    constexpr size_t OFF_WTD  = OFF_WTC + 3 * 512 * 512 * 2;            // 2,625,536
    constexpr size_t OFF_FTR  = OFF_WTD + 3 * 512 * 512 * 2;            // 4,198,400
    constexpr size_t OFF_HT   = OFF_FTR + (size_t)8 * 4098 * 512 * 2;   // 37,769,216
    constexpr size_t OFF_S2   = OFF_HT  + (size_t)8 * 4096 * 512 * 2;   // 71,323,648
    constexpr size_t NEED     = OFF_S2  + (size_t)8 * 4096 * 512 * 2;   // 104,878,080

    float* mean = (float*)d_ws;
    float* rstd = (float*)((char*)d_ws + 1024);

    if (ws_size >= NEED){
        char* ws = (char*)d_ws;
        int*   ia0 = (int*)  (ws + OFF_PREP + 0 * SZ_PREP);
        int*   ia1 = (int*)  (ws + OFF_PREP + 1 * SZ_PREP);
        int*   ic0 = (int*)  (ws + OFF_PREP + 2 * SZ_PREP);
        int*   ic1 = (int*)  (ws + OFF_PREP + 3 * SZ_PREP);
        float* wa0 = (float*)(ws + OFF_PREP + 4 * SZ_PREP);
        float* wa1 = (float*)(ws + OFF_PREP + 5 * SZ_PREP);
        float* wc0 = (float*)(ws + OFF_PREP + 6 * SZ_PREP);
        float* wc1 = (float*)(ws + OFF_PREP + 7 * SZ_PREP);
        bf16* wtc = (bf16*)(ws + OFF_WTC);
        bf16* wtd = (bf16*)(ws + OFF_WTD);
        bf16* ftr = (bf16*)(ws + OFF_FTR);    // reused as S0 after conv1
        bf16* ht  = (bf16*)(ws + OFF_HT);
        bf16* S2  = (bf16*)(ws + OFF_S2);
        bf16* S0  = ftr;

        k_transpose<<<dim3(64, 8, 8), 256, 0, stream>>>(feat, ftr);
        k_zpad     <<<32, 256, 0, stream>>>(ftr);
        k_wcvt     <<<3072, 256, 0, stream>>>(conv_w, wtc);
        k_wcvt     <<<3072, 256, 0, stream>>>(dcn_w, wtd);
        k_conv1g   <<<dim3(32, 4, 8), 256, 0, stream>>>(ftr, wtc, conv_b, ht);
        k_gnstats2 <<<256, 256, 0, stream>>>(ht, mean, rstd);
        k_gnapply2 <<<8192, 256, 0, stream>>>(ht, mean, rstd, gn_g, gn_b);
        k_prep     <<<128, 256, 0, stream>>>(locs, d_in[10], ia0, ia1, ic0, ic1, wa0, wa1, wc0, wc1);
        k_sample   <<<dim3(256, 8), 256, 0, stream>>>(ht, ia0, ia1, ic0, ic1, wa0, wa1, wc0, wc1, S0, S2);
        k_deformg  <<<dim3(32, 4, 8), 256, 0, stream>>>(S0, ht, S2, wtd, dcn_b, offset_feat);
        k_outinit  <<<256, 256, 0, stream>>>(out_b, offset);
        k_outconv  <<<dim3(16, 8, 8), 256, 0, stream>>>(offset_feat, out_w, offset);
    } else {
        bf16* h = (bf16*)((char*)d_ws + 4096);
        dim3 gemm_grid(Tt / TN, Cc / TM, Nn);
        k_conv1_fb  <<<gemm_grid, 256, 0, stream>>>(feat, conv_w, conv_b, h);
        k_gnstats_fb<<<Nn * Gg, 256, 0, stream>>>(h, mean, rstd);
        k_gnapply_fb<<<(Nn * Cc * Tt) / 256, 256, 0, stream>>>(h, mean, rstd, gn_g, gn_b);
        k_deform_fb <<<gemm_grid, 256, 0, stream>>>(h, locs, dcn_w, dcn_b, d_in[10], offset_feat);
        k_outinit   <<<256, 256, 0, stream>>>(out_b, offset);
        k_outconv   <<<dim3(16, 8, 8), 256, 0, stream>>>(offset_feat, out_w, offset);
    }
}

// Round 7
// 333.782 us; speedup vs baseline: 76.0677x; 1.9775x over previous
//
#include <hip/hip_runtime.h>
#include <hip/hip_bf16.h>

typedef __hip_bfloat16 bf16;
typedef __attribute__((ext_vector_type(8))) short short8;
typedef __attribute__((ext_vector_type(4))) float float4v;

constexpr int Nn = 8, Cc = 512, Tt = 4096, Gg = 32, CPG = 16;
constexpr float EPS = 1e-5f;

__device__ __forceinline__ float b2f(bf16 x){ return __bfloat162float(x); }
__device__ __forceinline__ bf16  f2b(float x){ return __float2bfloat16(x); }
__device__ __forceinline__ short f2s(float x){
    union { bf16 b; short s; } u; u.b = f2b(x); return u.s;
}
__device__ __forceinline__ float s2f(short x){
    union { short s; bf16 b; } u; u.s = x; return b2f(u.b);
}

__device__ __forceinline__ float stride_val(const void* sp){
    int si = *(const int*)sp;
    if (si >= 1 && si <= 100000) return (float)si;
    float sf = *(const float*)sp;
    if (sf >= 0.5f && sf <= 1.0e5f) return sf;
    return 8.0f;
}

// async global->LDS, 16B per lane; LDS dest = wave-uniform base + lane*16
__device__ __forceinline__ void gld16(const void* g, void* l){
    __builtin_amdgcn_global_load_lds(
        (const __attribute__((address_space(1))) unsigned int*)g,
        (__attribute__((address_space(3))) unsigned int*)l, 16, 0, 0);
}

// ---- P1: transpose feat fp32 [n][i][t] -> ftr bf16 [n][t+1][i] (pad rows 0,4097) ----
__global__ void k_transpose(const float* __restrict__ feat, bf16* __restrict__ ftr){
    __shared__ float L[64 * 65];
    int t0 = blockIdx.x * 64, i0 = blockIdx.y * 64, n = blockIdx.z;
    int tid = threadIdx.x;
    const float* fb = feat + ((size_t)n * Cc + i0) * Tt + t0;
    #pragma unroll
    for (int it = 0; it < 4; ++it){
        int p = tid + it * 256;
        int i = p >> 4, t4 = (p & 15) * 4;
        float4v v = *(const float4v*)&fb[(size_t)i * Tt + t4];
        L[(t4 + 0) * 65 + i] = v.x;
        L[(t4 + 1) * 65 + i] = v.y;
        L[(t4 + 2) * 65 + i] = v.z;
        L[(t4 + 3) * 65 + i] = v.w;
    }
    __syncthreads();
    #pragma unroll
    for (int it = 0; it < 2; ++it){
        int p = tid + it * 256;
        int t = p >> 3, s = p & 7;
        short8 sv;
        #pragma unroll
        for (int j = 0; j < 8; ++j) sv[j] = f2s(L[t * 65 + s * 8 + j]);
        *(short8*)&ftr[((size_t)n * 4098 + t0 + t + 1) * Cc + i0 + s * 8] = sv;
    }
}

__global__ void k_zpad(bf16* __restrict__ ftr){
    int p = blockIdx.x * 256 + threadIdx.x;      // 8192
    int n = p >> 10, r = (p >> 9) & 1, i = p & 511;
    ftr[((size_t)n * 4098 + (r ? 4097 : 0)) * Cc + i] = f2b(0.f);
}

// ---- P2: weights fp32 [o][i][k] -> bf16 [k][o][i] ----
__global__ void k_wcvt(const float* __restrict__ w, bf16* __restrict__ wt){
    int p = blockIdx.x * 256 + threadIdx.x;      // 786432
    int k = p >> 18, rest = p & 262143;
    wt[p] = f2b(w[(size_t)rest * 3 + k]);
}

// =====================================================================
// m97-style GEMM cores: LDS staging via global_load_lds + swizzled cols
// LDS(r,s) holds G(r, s ^ ((r>>1)&3)); frag read uses same xor.
// =====================================================================

// ---- conv1: C[o][t] = sum_taps W_tap[o][i] * ftr[t+tap][i]; epilogue -> ht[n][t][o] bf16
__global__ __launch_bounds__(256, 4) void k_conv1g(const bf16* __restrict__ ftr,
        const bf16* __restrict__ wtc, const float* __restrict__ bias, bf16* __restrict__ ht){
    __shared__ __align__(16) short As[128 * 32];
    __shared__ __align__(16) short Bs[128 * 32];
    __shared__ float Lt[32 * 132];
    int t0 = blockIdx.x * 128, o0 = blockIdx.y * 128, n = blockIdx.z;
    int tid = threadIdx.x, wid = tid >> 6, lane = tid & 63;
    int quad = lane >> 4, l15 = lane & 15;
    int rlo  = lane >> 2;                            // staging row within 16
    int colo = 8 * ((lane & 3) ^ ((lane >> 3) & 3)); // swizzled staging col (shorts)
    int sgf  = 8 * (quad ^ ((lane >> 1) & 3));       // swizzled frag col (shorts)

    float4v acc[2][8];
    #pragma unroll
    for (int m = 0; m < 2; ++m)
        #pragma unroll
        for (int f = 0; f < 8; ++f) acc[m][f] = (float4v){0.f,0.f,0.f,0.f};

    const short* ABp = (const short*)wtc + (size_t)o0 * 512;
    const short* BBp = (const short*)ftr + ((size_t)n * 4098 + t0) * 512;
    int r0 = wid * 32;

    for (int tap = 0; tap < 3; ++tap){
        const short* Ab = ABp + (size_t)tap * 262144;
        const short* Bb = BBp + (size_t)tap * 512;
        for (int ic = 0; ic < 512; ic += 32){
            gld16(Ab + (size_t)(r0 + rlo)      * 512 + ic + colo, As + r0 * 32);
            gld16(Ab + (size_t)(r0 + 16 + rlo) * 512 + ic + colo, As + (r0 + 16) * 32);
            gld16(Bb + (size_t)(r0 + rlo)      * 512 + ic + colo, Bs + r0 * 32);
            gld16(Bb + (size_t)(r0 + 16 + rlo) * 512 + ic + colo, Bs + (r0 + 16) * 32);
            __syncthreads();
            short8 a0 = *(const short8*)&As[(r0 + l15) * 32 + sgf];
            short8 a1 = *(const short8*)&As[(r0 + 16 + l15) * 32 + sgf];
            #pragma unroll
            for (int f = 0; f < 8; ++f){
                short8 b = *(const short8*)&Bs[(f * 16 + l15) * 32 + sgf];
                acc[0][f] = __builtin_amdgcn_mfma_f32_16x16x32_bf16(a0, b, acc[0][f], 0, 0, 0);
                acc[1][f] = __builtin_amdgcn_mfma_f32_16x16x32_bf16(a1, b, acc[1][f], 0, 0, 0);
            }
            __syncthreads();
        }
    }
    // epilogue: +bias, transpose [o][t] -> ht[n][t][o], bf16
    #pragma unroll
    for (int pass = 0; pass < 4; ++pass){
        __syncthreads();
        #pragma unroll
        for (int m = 0; m < 2; ++m){
            #pragma unroll
            for (int fi = 0; fi < 2; ++fi){
                int f = pass * 2 + fi;
                int tl = fi * 16 + l15;
                int ob = wid * 32 + m * 16 + quad * 4;
                #pragma unroll
                for (int r = 0; r < 4; ++r)
                    Lt[tl * 132 + ob + r] = acc[m][f][r] + bias[o0 + ob + r];
            }
        }
        __syncthreads();
        #pragma unroll
        for (int it = 0; it < 2; ++it){
            int p = tid + it * 256;
            int tl = p >> 4, s = p & 15;
            short8 sv;
            #pragma unroll
            for (int j = 0; j < 8; ++j) sv[j] = f2s(Lt[tl * 132 + s * 8 + j]);
            *(short8*)&ht[((size_t)n * Tt + t0 + pass * 32 + tl) * Cc + o0 + s * 8] = sv;
        }
    }
}

// ---- GN stats on ht[n][t][i] ----
__global__ void k_gnstats2(const bf16* __restrict__ ht, float* __restrict__ mean,
                           float* __restrict__ rstd){
    int blk = blockIdx.x;                  // n*32+g
    int n = blk >> 5, g = blk & 31;
    const bf16* base = ht + (size_t)n * Tt * Cc + g * 16 + (threadIdx.x & 1) * 8;
    float s = 0.f, ss = 0.f;
    for (int r = threadIdx.x >> 1; r < Tt; r += 128){
        short8 v = *(const short8*)&base[(size_t)r * Cc];
        #pragma unroll
        for (int j = 0; j < 8; ++j){ float f = s2f(v[j]); s += f; ss += f * f; }
    }
    __shared__ float sh[512];
    sh[threadIdx.x] = s; sh[256 + threadIdx.x] = ss;
    __syncthreads();
    for (int off = 128; off > 0; off >>= 1){
        if (threadIdx.x < off){
            sh[threadIdx.x] += sh[threadIdx.x + off];
            sh[256 + threadIdx.x] += sh[256 + threadIdx.x + off];
        }
        __syncthreads();
    }
    if (threadIdx.x == 0){
        float m = sh[0] / (float)(CPG * Tt);
        float v = sh[256] / (float)(CPG * Tt) - m * m;
        mean[blk] = m; rstd[blk] = rsqrtf(v + EPS);
    }
}

// ---- GN apply + relu, in place on ht ----
__global__ void k_gnapply2(bf16* __restrict__ ht, const float* __restrict__ mean,
        const float* __restrict__ rstd, const float* __restrict__ gamma,
        const float* __restrict__ beta){
    int p = blockIdx.x * 256 + threadIdx.x;
    int s = p & 63, row = p >> 6;             // row = n*4096+t
    int n = row >> 12;
    int ib = s * 8;
    int blk = n * 32 + (ib >> 4);
    float mu = mean[blk], rs = rstd[blk];
    short8 v = *(short8*)&ht[(size_t)row * Cc + ib];
    short8 o;
    #pragma unroll
    for (int j = 0; j < 8; ++j){
        int c = ib + j;
        float f = (s2f(v[j]) - mu) * rs * gamma[c] + beta[c];
        o[j] = f2s(fmaxf(f, 0.f));
    }
    *(short8*)&ht[(size_t)row * Cc + ib] = o;
}

// ---- per-(n,t) deform sampling params ----
__global__ void k_prep(const float* __restrict__ locs, const void* __restrict__ sp,
        int* __restrict__ ia0, int* __restrict__ ia1, int* __restrict__ ic0,
        int* __restrict__ ic1, float* __restrict__ wa0, float* __restrict__ wa1,
        float* __restrict__ wc0, float* __restrict__ wc1){
    int idx = blockIdx.x * 256 + threadIdx.x;   // 32768
    int t = idx & 4095, n = idx >> 12;
    float s = stride_val(sp);
    float l1 = locs[((size_t)n * 2 + 0) * Tt + t];
    float l2 = locs[((size_t)n * 2 + 1) * Tt + t];
    float y1 = (0.9f * l1 + 0.1f * l1) / s;     // match ref GRAD_MUL arithmetic
    float y2 = (0.9f * l2 + 0.1f * l2) / s;
    float pos0 = (float)(t - 1) - y1;
    float pos2 = (float)(t + 1) + y2;
    float p0f = floorf(pos0), p2f = floorf(pos2);
    float w1 = pos0 - p0f, w2 = pos2 - p2f;
    int a0 = (int)p0f, a1 = a0 + 1, c0 = (int)p2f, c1 = c0 + 1;
    wa0[idx] = (a0 >= 0 && a0 < Tt) ? (1.f - w1) : 0.f;
    wa1[idx] = (a1 >= 0 && a1 < Tt) ? w1 : 0.f;
    wc0[idx] = (c0 >= 0 && c0 < Tt) ? (1.f - w2) : 0.f;
    wc1[idx] = (c1 >= 0 && c1 < Tt) ? w2 : 0.f;
    ia0[idx] = min(max(a0, 0), Tt - 1);
    ia1[idx] = min(max(a1, 0), Tt - 1);
    ic0[idx] = min(max(c0, 0), Tt - 1);
    ic1[idx] = min(max(c1, 0), Tt - 1);
}

// ---- materialize S0/S2 (gather+lerp, coalesced in i) ----
__global__ void k_sample(const bf16* __restrict__ ht, const int* __restrict__ ia0,
        const int* __restrict__ ia1, const int* __restrict__ ic0, const int* __restrict__ ic1,
        const float* __restrict__ wa0, const float* __restrict__ wa1,
        const float* __restrict__ wc0, const float* __restrict__ wc1,
        bf16* __restrict__ S0, bf16* __restrict__ S2){
    int n = blockIdx.y;
    int t0 = blockIdx.x * 16;
    int lane = threadIdx.x & 63, slot = threadIdx.x >> 6;
    const bf16* hb = ht + (size_t)n * Tt * Cc;
    #pragma unroll
    for (int rr = 0; rr < 4; ++rr){
        int t = t0 + slot * 4 + rr;
        int idx = n * Tt + t;
        {
            short8 lo = *(const short8*)&hb[(size_t)ia0[idx] * Cc + lane * 8];
            short8 hi = *(const short8*)&hb[(size_t)ia1[idx] * Cc + lane * 8];
            float w0 = wa0[idx], w1 = wa1[idx];
            short8 o;
            #pragma unroll
            for (int j = 0; j < 8; ++j) o[j] = f2s(w0 * s2f(lo[j]) + w1 * s2f(hi[j]));
            *(short8*)&S0[(size_t)idx * Cc + lane * 8] = o;
        }
        {
            short8 lo = *(const short8*)&hb[(size_t)ic0[idx] * Cc + lane * 8];
            short8 hi = *(const short8*)&hb[(size_t)ic1[idx] * Cc + lane * 8];
            float w0 = wc0[idx], w1 = wc1[idx];
            short8 o;
            #pragma unroll
            for (int j = 0; j < 8; ++j) o[j] = f2s(w0 * s2f(lo[j]) + w1 * s2f(hi[j]));
            *(short8*)&S2[(size_t)idx * Cc + lane * 8] = o;
        }
    }
}

// ---- deform GEMM over 3 B-tensors; +bias, relu, fp32 out [n][o][t] ----
__global__ __launch_bounds__(256, 4) void k_deformg(const bf16* __restrict__ S0,
        const bf16* __restrict__ ht, const bf16* __restrict__ S2,
        const bf16* __restrict__ wtd, const float* __restrict__ bias,
        float* __restrict__ out){
    __shared__ __align__(16) short As[128 * 32];
    __shared__ __align__(16) short Bs[128 * 32];
    int t0 = blockIdx.x * 128, o0 = blockIdx.y * 128, n = blockIdx.z;
    int tid = threadIdx.x, wid = tid >> 6, lane = tid & 63;
    int quad = lane >> 4, l15 = lane & 15;
    int rlo  = lane >> 2;
    int colo = 8 * ((lane & 3) ^ ((lane >> 3) & 3));
    int sgf  = 8 * (quad ^ ((lane >> 1) & 3));

    float4v acc[2][8];
    #pragma unroll
    for (int m = 0; m < 2; ++m)
        #pragma unroll
        for (int f = 0; f < 8; ++f) acc[m][f] = (float4v){0.f,0.f,0.f,0.f};

    size_t boff = ((size_t)n * Tt + t0) * 512;
    const short* Bb3[3] = { (const short*)S0 + boff, (const short*)ht + boff,
                            (const short*)S2 + boff };
    const short* ABp = (const short*)wtd + (size_t)o0 * 512;
    int r0 = wid * 32;

    for (int tap = 0; tap < 3; ++tap){
        const short* Ab = ABp + (size_t)tap * 262144;
        const short* Bb = Bb3[tap];
        for (int ic = 0; ic < 512; ic += 32){
            gld16(Ab + (size_t)(r0 + rlo)      * 512 + ic + colo, As + r0 * 32);
            gld16(Ab + (size_t)(r0 + 16 + rlo) * 512 + ic + colo, As + (r0 + 16) * 32);
            gld16(Bb + (size_t)(r0 + rlo)      * 512 + ic + colo, Bs + r0 * 32);
            gld16(Bb + (size_t)(r0 + 16 + rlo) * 512 + ic + colo, Bs + (r0 + 16) * 32);
            __syncthreads();
            short8 a0 = *(const short8*)&As[(r0 + l15) * 32 + sgf];
            short8 a1 = *(const short8*)&As[(r0 + 16 + l15) * 32 + sgf];
            #pragma unroll
            for (int f = 0; f < 8; ++f){
                short8 b = *(const short8*)&Bs[(f * 16 + l15) * 32 + sgf];
                acc[0][f] = __builtin_amdgcn_mfma_f32_16x16x32_bf16(a0, b, acc[0][f], 0, 0, 0);
                acc[1][f] = __builtin_amdgcn_mfma_f32_16x16x32_bf16(a1, b, acc[1][f], 0, 0, 0);
            }
            __syncthreads();
        }
    }
    float* ob = out + (size_t)n * Cc * Tt;
    #pragma unroll
    for (int m = 0; m < 2; ++m){
        int ob0 = o0 + wid * 32 + m * 16 + quad * 4;
        #pragma unroll
        for (int r = 0; r < 4; ++r){
            float bs = bias[ob0 + r];
            size_t row = (size_t)(ob0 + r) * Tt;
            #pragma unroll
            for (int f = 0; f < 8; ++f)
                ob[row + t0 + f * 16 + l15] = fmaxf(acc[m][f][r] + bs, 0.f);
        }
    }
}

// ---- Stage 4: conv1d 512->2, K-split + atomics ----
__global__ void k_outinit(const float* __restrict__ ob, float* __restrict__ out){
    int idx = blockIdx.x * 256 + threadIdx.x;      // 65536
    out[idx] = ob[(idx >> 12) & 1];
}

__global__ void k_outconv(const float* __restrict__ x, const float* __restrict__ w,
                          float* __restrict__ out){
    int t  = blockIdx.x * 256 + threadIdx.x;
    int i0 = blockIdx.y * 64;
    int n  = blockIdx.z;
    const float* xb = x + (size_t)n * Cc * Tt;
    float a0 = 0.f, a1 = 0.f;
    bool tm = (t > 0), tp = (t < Tt - 1);
    for (int i = i0; i < i0 + 64; ++i){
        const float* xr = xb + (size_t)i * Tt + t;
        float xm = tm ? xr[-1] : 0.f;
        float x0 = xr[0];
        float xp = tp ? xr[1] : 0.f;
        const float* w0 = w + i * 3;
        const float* w1 = w + Cc * 3 + i * 3;
        a0 += xm * w0[0] + x0 * w0[1] + xp * w0[2];
        a1 += xm * w1[0] + x0 * w1[1] + xp * w1[2];
    }
    atomicAdd(&out[((size_t)n * 2 + 0) * Tt + t], a0);
    atomicAdd(&out[((size_t)n * 2 + 1) * Tt + t], a1);
}

// ================================ HOST ================================
extern "C" void kernel_launch(void* const* d_in, const int* in_sizes, int n_in,
                              void* d_out, int out_size, void* d_ws, size_t ws_size,
                              hipStream_t stream) {
    const float* feat   = (const float*)d_in[0];
    const float* locs   = (const float*)d_in[1];
    const float* conv_w = (const float*)d_in[2];
    const float* conv_b = (const float*)d_in[3];
    const float* gn_g   = (const float*)d_in[4];
    const float* gn_b   = (const float*)d_in[5];
    const float* dcn_w  = (const float*)d_in[6];
    const float* dcn_b  = (const float*)d_in[7];
    const float* out_w  = (const float*)d_in[8];
    const float* out_b  = (const float*)d_in[9];

    float* offset      = (float*)d_out;                        // (8,2,4096) fp32
    float* offset_feat = (float*)d_out + (size_t)Nn * 2 * Tt;  // (8,512,4096) fp32

    constexpr size_t SZ_PREP = 32768 * 4;
    constexpr size_t OFF_PREP = 4096;
    constexpr size_t OFF_WTC  = OFF_PREP + 8 * SZ_PREP;
    constexpr size_t OFF_WTD  = OFF_WTC + 3 * 512 * 512 * 2;
    constexpr size_t OFF_FTR  = OFF_WTD + 3 * 512 * 512 * 2;
    constexpr size_t OFF_HT   = OFF_FTR + (size_t)8 * 4098 * 512 * 2;
    constexpr size_t OFF_S2   = OFF_HT  + (size_t)8 * 4096 * 512 * 2;

    float* mean = (float*)d_ws;
    float* rstd = (float*)((char*)d_ws + 1024);

    char* ws = (char*)d_ws;
    int*   ia0 = (int*)  (ws + OFF_PREP + 0 * SZ_PREP);
    int*   ia1 = (int*)  (ws + OFF_PREP + 1 * SZ_PREP);
    int*   ic0 = (int*)  (ws + OFF_PREP + 2 * SZ_PREP);
    int*   ic1 = (int*)  (ws + OFF_PREP + 3 * SZ_PREP);
    float* wa0 = (float*)(ws + OFF_PREP + 4 * SZ_PREP);
    float* wa1 = (float*)(ws + OFF_PREP + 5 * SZ_PREP);
    float* wc0 = (float*)(ws + OFF_PREP + 6 * SZ_PREP);
    float* wc1 = (float*)(ws + OFF_PREP + 7 * SZ_PREP);
    bf16* wtc = (bf16*)(ws + OFF_WTC);
    bf16* wtd = (bf16*)(ws + OFF_WTD);
    bf16* ftr = (bf16*)(ws + OFF_FTR);    // reused as S0 after conv1
    bf16* ht  = (bf16*)(ws + OFF_HT);
    bf16* S2  = (bf16*)(ws + OFF_S2);
    bf16* S0  = ftr;

    k_transpose<<<dim3(64, 8, 8), 256, 0, stream>>>(feat, ftr);
    k_zpad     <<<32, 256, 0, stream>>>(ftr);
    k_wcvt     <<<3072, 256, 0, stream>>>(conv_w, wtc);
    k_wcvt     <<<3072, 256, 0, stream>>>(dcn_w, wtd);
    k_conv1g   <<<dim3(32, 4, 8), 256, 0, stream>>>(ftr, wtc, conv_b, ht);
    k_gnstats2 <<<256, 256, 0, stream>>>(ht, mean, rstd);
    k_gnapply2 <<<8192, 256, 0, stream>>>(ht, mean, rstd, gn_g, gn_b);
    k_prep     <<<128, 256, 0, stream>>>(locs, d_in[10], ia0, ia1, ic0, ic1, wa0, wa1, wc0, wc1);
    k_sample   <<<dim3(256, 8), 256, 0, stream>>>(ht, ia0, ia1, ic0, ic1, wa0, wa1, wc0, wc1, S0, S2);
    k_deformg  <<<dim3(32, 4, 8), 256, 0, stream>>>(S0, ht, S2, wtd, dcn_b, offset_feat);
    k_outinit  <<<256, 256, 0, stream>>>(out_b, offset);
    k_outconv  <<<dim3(16, 8, 8), 256, 0, stream>>>(offset_feat, out_w, offset);
}